// Round 10
// baseline (304.882 us; speedup 1.0000x reference)
//
#include <hip/hip_runtime.h>
#include <hip/hip_fp16.h>

// out[b, m, r] = x[b, ind[r,m]] * filters[r, ind[r,m]]
// rem = m*512+r; out flat = b*65536 + rem. idx table fixed across rows.
//
// map9: bucket the 65536 (rem, idx, w) entries by idx>>12 into 16 chunks at
// build time. Per row: 16-stage pipeline {stage 8KB x-chunk (dbuf) || compute
// chunk entries: LDS gather -> mul -> fp16 scatter into 128KB LDS out-buffer}
// then one coalesced sweep out-buffer -> global fp32.
// vmcnt issue-order discipline (R8 lesson): per iter, short L2 tab loads for
// chunk c+1 are issued BEFORE the long HBM x-load for chunk c+2, so counted
// waits for tab never drain the HBM load.

constexpr int D_ROW = 128;
constexpr int D_COL = 512;
constexpr int D_ALL = D_ROW * D_COL;   // 65536
constexpr int BATCH = 1024;
constexpr int ROWS_PER_BLK = 4;
constexpr int NCHUNK = 16;
constexpr int CHUNK  = 4096;           // x elems per chunk (8 KB fp16)
constexpr int CAP    = 8192;           // padded table capacity per chunk

// ---------------- build: bucketed entry table ----------------
// ws: unsigned gcur[16]; u64 tab[16*CAP]
__global__ void k_zero(unsigned* gcur) {
    if (threadIdx.x < NCHUNK) gcur[threadIdx.x] = 0;
}

__global__ void __launch_bounds__(256)
k_build(const float* __restrict__ filters,
        const int*   __restrict__ ind,
        unsigned* __restrict__ gcur,
        unsigned long long* __restrict__ tab) {
    __shared__ unsigned cnt[NCHUNK], base[NCHUNK];
    const int t = threadIdx.x;
    const int rem = blockIdx.x * 256 + t;          // 0..65535
    if (t < NCHUNK) cnt[t] = 0;
    __syncthreads();
    const int m = rem >> 9, r = rem & 511;
    const int idx = ind[r * D_ROW + m];
    const float w = filters[(size_t)r * D_ALL + idx];
    const unsigned short w16 = __half_as_ushort(__float2half_rn(w));
    const unsigned long long e =
        ((unsigned long long)w16 << 32) | ((unsigned)idx << 16) | (unsigned)rem;
    const int bin = idx >> 12;
    const unsigned local = atomicAdd(&cnt[bin], 1u);
    __syncthreads();
    if (t < NCHUNK) base[t] = atomicAdd(&gcur[t], cnt[t]);
    __syncthreads();
    tab[(size_t)bin * CAP + base[bin] + local] = e;
}

// ---------------- main ----------------
__device__ __forceinline__ void lds_barrier() {
    asm volatile("s_waitcnt lgkmcnt(0)" ::: "memory");
    __builtin_amdgcn_s_barrier();
}

__global__ void __launch_bounds__(1024)
map9(const float* __restrict__ x,
     const unsigned* __restrict__ gcur,
     const unsigned long long* __restrict__ tab,
     float* __restrict__ out) {
    __shared__ __half outbuf[D_ALL];        // 128 KB
    __shared__ __half xbuf[2][CHUNK];       // 16 KB
    const int t = threadIdx.x;              // 0..1023
    const int row0 = blockIdx.x * ROWS_PER_BLK;

    // counts (uniform -> SGPR/SMEM, lgkm counter, no vmcnt coupling)
    int ncnt[NCHUNK];
    #pragma unroll
    for (int c = 0; c < NCHUNK; ++c) {
        int n = (int)gcur[c];
        ncnt[c] = n > CAP ? CAP : n;
    }

    // Prologue issue order: tab(chunk0) [L2, oldest], then x chunk0, chunk1 [HBM].
    unsigned long long treg[2][8];
    #pragma unroll
    for (int e = 0; e < 8; ++e) {
        int s = e * 1024 + t;
        if (s < ncnt[0]) treg[0][e] = tab[s];
    }
    __builtin_amdgcn_sched_barrier(0);
    float4 creg[2];
    creg[0] = reinterpret_cast<const float4*>(x + ((size_t)row0 << 16))[t];
    creg[1] = reinterpret_cast<const float4*>(x + ((size_t)row0 << 16) + CHUNK)[t];
    __builtin_amdgcn_sched_barrier(0);

    #pragma unroll 1
    for (int k = 0; k < ROWS_PER_BLK; ++k) {
        float* ob = out + ((size_t)(row0 + k) << 16);

        #pragma unroll
        for (int c = 0; c < NCHUNK; ++c) {
            // ---- stage chunk c from creg[c&1] into xbuf[c&1] ----
            {
                float4 v = creg[c & 1];
                __half2 h0 = __floats2half2_rn(v.x, v.y);
                __half2 h1 = __floats2half2_rn(v.z, v.w);
                uint2 u;
                u.x = *reinterpret_cast<unsigned*>(&h0);
                u.y = *reinterpret_cast<unsigned*>(&h1);
                *reinterpret_cast<uint2*>(&xbuf[c & 1][t * 4]) = u;
            }
            // ---- issue tab prefetch for chunk c+1 (short L2 loads first) ----
            {
                const int nc = (c + 1) & 15;
                const unsigned long long* tsrc = tab + (size_t)nc * CAP;
                const int nn = ncnt[nc];
                #pragma unroll
                for (int e = 0; e < 8; ++e) {
                    int s = e * 1024 + t;
                    if (s < nn) treg[(c + 1) & 1][e] = tsrc[s];
                }
            }
            __builtin_amdgcn_sched_barrier(0);
            // ---- issue x load for chunk c+2 (long HBM load last) ----
            {
                // global chunk G = k*16+c; target G+2
                int nk, nc;
                if (c < 14)      { nk = k; nc = c + 2; }
                else             { nk = (k + 1 < ROWS_PER_BLK) ? k + 1 : 0; nc = (c + 2) & 15; }
                const float4* src = reinterpret_cast<const float4*>(
                    x + ((size_t)(row0 + nk) << 16) + nc * CHUNK);
                creg[c & 1] = src[t];
            }
            __builtin_amdgcn_sched_barrier(0);

            lds_barrier();   // xbuf[c&1] visible to all waves

            // ---- compute chunk c from treg[c&1] ----
            {
                const int n = ncnt[c];
                #pragma unroll
                for (int e = 0; e < 8; ++e) {
                    int s = e * 1024 + t;
                    if (s < n) {
                        unsigned long long v = treg[c & 1][e];
                        unsigned lo  = (unsigned)v;
                        unsigned rem = lo & 0xffffu;
                        unsigned loc = (lo >> 16) & 4095u;
                        float xv = __half2float(xbuf[c & 1][loc]);
                        float res = xv * __half2float(
                            __ushort_as_half((unsigned short)(v >> 32)));
                        outbuf[rem] = __float2half_rn(res);
                    }
                }
            }
        }

        lds_barrier();   // all outbuf scatter-writes visible before sweep

        // ---- sweep: outbuf (fp16) -> out (fp32), fully coalesced ----
        #pragma unroll
        for (int i = 0; i < 8; ++i) {
            uint4 u = *reinterpret_cast<const uint4*>(&outbuf[i * 8192 + t * 8]);
            __half2 a = *reinterpret_cast<__half2*>(&u.x);
            __half2 b = *reinterpret_cast<__half2*>(&u.y);
            __half2 cc = *reinterpret_cast<__half2*>(&u.z);
            __half2 d = *reinterpret_cast<__half2*>(&u.w);
            float4 f0, f1;
            f0.x = __half2float(a.x);  f0.y = __half2float(a.y);
            f0.z = __half2float(b.x);  f0.w = __half2float(b.y);
            f1.x = __half2float(cc.x); f1.y = __half2float(cc.y);
            f1.z = __half2float(d.x);  f1.w = __half2float(d.y);
            *reinterpret_cast<float4*>(ob + i * 8192 + t * 8)     = f0;
            *reinterpret_cast<float4*>(ob + i * 8192 + t * 8 + 4) = f1;
        }
        // no trailing barrier needed: next row's first lds_barrier orders
        // sweep reads (before it) vs chunk-0 outbuf writes (after it).
    }
}

// ---------------- fallbacks ----------------
__global__ void __launch_bounds__(256)
build_pk(const float* __restrict__ filters,
         const int*   __restrict__ ind,
         unsigned* __restrict__ pk) {
    int t = blockIdx.x * 256 + threadIdx.x;
    if (t >= D_ALL) return;
    int m = t >> 9, r = t & 511;
    int idx = ind[r * D_ROW + m];
    __half hw = __float2half_rn(filters[(size_t)r * D_ALL + idx]);
    pk[t] = ((unsigned)__half_as_ushort(hw) << 16) | (unsigned)idx;
}

__device__ __forceinline__ float map_one(const __half* xs, unsigned p) {
    return __half2float(xs[p & 0xffffu]) *
           __half2float(__ushort_as_half((unsigned short)(p >> 16)));
}
__device__ __forceinline__ unsigned h2bits(float a, float b) {
    __half2 h = __floats2half2_rn(a, b);
    return *reinterpret_cast<unsigned*>(&h);
}

__global__ void __launch_bounds__(1024, 4)
map8(const float* __restrict__ x, const uint4* __restrict__ pk4,
     float* __restrict__ out) {
    __shared__ __half xs[D_ALL];
    const int t = threadIdx.x;
    const int row0 = blockIdx.x * ROWS_PER_BLK;
    float4 buf[16];
    {
        const float4* src = reinterpret_cast<const float4*>(x + ((size_t)row0 << 16));
        #pragma unroll
        for (int i = 0; i < 8; ++i) {
            buf[2 * i]     = src[i * 2048 + t * 2];
            buf[2 * i + 1] = src[i * 2048 + t * 2 + 1];
        }
    }
    #pragma unroll
    for (int k = 0; k < ROWS_PER_BLK; ++k) {
        #pragma unroll
        for (int i = 0; i < 8; ++i) {
            uint4 u;
            u.x = h2bits(buf[2 * i].x,     buf[2 * i].y);
            u.y = h2bits(buf[2 * i].z,     buf[2 * i].w);
            u.z = h2bits(buf[2 * i + 1].x, buf[2 * i + 1].y);
            u.w = h2bits(buf[2 * i + 1].z, buf[2 * i + 1].w);
            *reinterpret_cast<uint4*>(xs + (size_t)(i * 2048 + t * 2) * 4) = u;
        }
        lds_barrier();
        float* ob = out + ((size_t)(row0 + k) << 16);
        #pragma unroll 4
        for (int j = 0; j < 16; ++j) {
            uint4 p = pk4[j * 1024 + t];
            float4 r;
            r.x = map_one(xs, p.x); r.y = map_one(xs, p.y);
            r.z = map_one(xs, p.z); r.w = map_one(xs, p.w);
            *reinterpret_cast<float4*>(ob + j * 4096 + t * 4) = r;
        }
        __builtin_amdgcn_sched_barrier(0);
        if (k + 1 < ROWS_PER_BLK) {
            const float4* src = reinterpret_cast<const float4*>(
                x + ((size_t)(row0 + k + 1) << 16));
            #pragma unroll
            for (int i = 0; i < 8; ++i) {
                buf[2 * i]     = src[i * 2048 + t * 2];
                buf[2 * i + 1] = src[i * 2048 + t * 2 + 1];
            }
        }
        __builtin_amdgcn_sched_barrier(0);
        lds_barrier();
    }
}

__global__ void __launch_bounds__(256)
map_kernel_nows(const float* __restrict__ x,
                const float* __restrict__ filters,
                const int*   __restrict__ ind,
                float*       __restrict__ out) {
    size_t o = (size_t)blockIdx.x * 256 + threadIdx.x;
    if (o >= (size_t)BATCH * D_ALL) return;
    unsigned b = (unsigned)(o >> 16);
    unsigned rem = (unsigned)(o & 65535u);
    unsigned m = rem >> 9, r = rem & 511u;
    int idx = ind[r * D_ROW + m];
    out[o] = x[((size_t)b << 16) + idx] * filters[(size_t)r * D_ALL + idx];
}

extern "C" void kernel_launch(void* const* d_in, const int* in_sizes, int n_in,
                              void* d_out, int out_size, void* d_ws, size_t ws_size,
                              hipStream_t stream) {
    const float* x       = (const float*)d_in[0];
    const float* filters = (const float*)d_in[1];
    const int*   ind     = (const int*)d_in[2];
    float*       out     = (float*)d_out;

    const size_t need9 = 64 + (size_t)NCHUNK * CAP * sizeof(unsigned long long); // ~1 MB
    const size_t need8 = (size_t)D_ALL * sizeof(unsigned);                       // 256 KB
    if (ws_size >= need9) {
        unsigned* gcur = (unsigned*)d_ws;
        unsigned long long* tab = (unsigned long long*)((char*)d_ws + 64);
        k_zero<<<1, 64, 0, stream>>>(gcur);
        k_build<<<D_ALL / 256, 256, 0, stream>>>(filters, ind, gcur, tab);
        map9<<<BATCH / ROWS_PER_BLK, 1024, 0, stream>>>(x, gcur, tab, out);
    } else if (ws_size >= need8) {
        unsigned* pk = (unsigned*)d_ws;
        build_pk<<<D_ALL / 256, 256, 0, stream>>>(filters, ind, pk);
        map8<<<BATCH / ROWS_PER_BLK, 1024, 0, stream>>>(
            x, reinterpret_cast<const uint4*>(pk), out);
    } else {
        map_kernel_nows<<<(BATCH * (size_t)D_ALL) / 256, 256, 0, stream>>>(
            x, filters, ind, out);
    }
}

// Round 11
// 176.058 us; speedup vs baseline: 1.7317x; 1.7317x over previous
//
#include <hip/hip_runtime.h>
#include <hip/hip_fp16.h>

// out[b, m, r] = x[b, ind[r,m]] * filters[r, ind[r,m]]
// rem = m*512+r; out flat = b*65536 + rem. Index table fixed across rows.
//
// map10: counting-sort the 65536 (idx, rem, w16) entries by idx once per
// call. Main kernel (1 row/block): stream sorted table, gather x[idx] from
// GLOBAL fp32 (sorted -> quasi-sequential, line-friendly, L1-cached),
// scatter fp16 product into 128KB LDS outbuf by rem, one barrier, coalesced
// sweep outbuf -> out. No stage phase, no lockstep, 1 barrier/block.

constexpr int D_ROW = 128;
constexpr int D_COL = 512;
constexpr int D_ALL = D_ROW * D_COL;   // 65536
constexpr int BATCH = 1024;

__device__ __forceinline__ void lds_barrier() {
    asm volatile("s_waitcnt lgkmcnt(0)" ::: "memory");
    __builtin_amdgcn_s_barrier();
}

// ---------------- build: counting sort by idx ----------------
// ws: offs u32[65536] | part u32[64] (+pad) | idx_rem u32[65536] | w16 u16[65536]

__global__ void __launch_bounds__(1024)
k_zero(unsigned* __restrict__ offs) {
    offs[blockIdx.x * 1024 + threadIdx.x] = 0u;
}

__global__ void __launch_bounds__(1024)
k_hist(const int* __restrict__ ind, unsigned* __restrict__ offs) {
    const int rem = blockIdx.x * 1024 + threadIdx.x;    // 0..65535
    const int m = rem >> 9, r = rem & 511;
    const int idx = ind[r * D_ROW + m];
    atomicAdd(&offs[idx], 1u);
}

// Exclusive scan of each 1024-bin group in place; group totals -> part.
__global__ void __launch_bounds__(1024)
k_scan1(unsigned* __restrict__ offs, unsigned* __restrict__ part) {
    __shared__ unsigned s[1024];
    const int t = threadIdx.x;
    const int g = blockIdx.x * 1024 + t;
    const unsigned v = offs[g];
    s[t] = v;
    __syncthreads();
    #pragma unroll
    for (int d = 1; d < 1024; d <<= 1) {
        unsigned a = (t >= d) ? s[t - d] : 0u;
        __syncthreads();
        s[t] += a;
        __syncthreads();
    }
    offs[g] = s[t] - v;                      // exclusive prefix within group
    if (t == 1023) part[blockIdx.x] = s[t];  // group total
}

// Exclusive scan of the 64 group totals.
__global__ void __launch_bounds__(64)
k_scan2(unsigned* __restrict__ part) {
    __shared__ unsigned s[64];
    const int t = threadIdx.x;
    const unsigned v = part[t];
    s[t] = v;
    __syncthreads();
    #pragma unroll
    for (int d = 1; d < 64; d <<= 1) {
        unsigned a = (t >= d) ? s[t - d] : 0u;
        __syncthreads();
        s[t] += a;
        __syncthreads();
    }
    part[t] = s[t] - v;
}

__global__ void __launch_bounds__(1024)
k_scatter(const float* __restrict__ filters,
          const int*   __restrict__ ind,
          unsigned* __restrict__ offs,
          const unsigned* __restrict__ part,
          unsigned* __restrict__ idx_rem,
          unsigned short* __restrict__ wbuf) {
    const int rem = blockIdx.x * 1024 + threadIdx.x;    // 0..65535
    const int m = rem >> 9, r = rem & 511;
    const int idx = ind[r * D_ROW + m];
    const float w = filters[(size_t)r * D_ALL + idx];
    const unsigned pos = part[idx >> 10] + atomicAdd(&offs[idx], 1u);
    idx_rem[pos] = ((unsigned)idx << 16) | (unsigned)rem;
    wbuf[pos]    = __half_as_ushort(__float2half_rn(w));
}

// ---------------- main ----------------
__global__ void __launch_bounds__(1024)
map10(const float* __restrict__ x,
      const uint4* __restrict__ ir4,       // 4 packed (idx<<16|rem) per load
      const ushort4* __restrict__ w4a,     // 4 fp16 w per load
      float* __restrict__ out) {
    __shared__ __half outbuf[D_ALL];       // 128 KB
    const int t = threadIdx.x;             // 0..1023
    const float* xb = x + ((size_t)blockIdx.x << 16);
    float*       ob = out + ((size_t)blockIdx.x << 16);

    // Compute: 64 sorted entries/thread. Step window = 4096 entries across
    // the block -> x gather window ~16 KB, L1-resident, lines fully used.
    #pragma unroll 4
    for (int e = 0; e < 16; ++e) {
        const uint4   ir = ir4[e * 1024 + t];
        const ushort4 w4 = w4a[e * 1024 + t];
        const float f0 = xb[ir.x >> 16];
        const float f1 = xb[ir.y >> 16];
        const float f2 = xb[ir.z >> 16];
        const float f3 = xb[ir.w >> 16];
        outbuf[ir.x & 0xffffu] = __float2half_rn(
            f0 * __half2float(__ushort_as_half(w4.x)));
        outbuf[ir.y & 0xffffu] = __float2half_rn(
            f1 * __half2float(__ushort_as_half(w4.y)));
        outbuf[ir.z & 0xffffu] = __float2half_rn(
            f2 * __half2float(__ushort_as_half(w4.z)));
        outbuf[ir.w & 0xffffu] = __float2half_rn(
            f3 * __half2float(__ushort_as_half(w4.w)));
    }
    lds_barrier();   // rem is a permutation -> outbuf fully written

    // Sweep: fp16 outbuf -> fp32 out, fully coalesced.
    #pragma unroll
    for (int i = 0; i < 8; ++i) {
        uint4 u = *reinterpret_cast<const uint4*>(&outbuf[i * 8192 + t * 8]);
        __half2 a = *reinterpret_cast<__half2*>(&u.x);
        __half2 b = *reinterpret_cast<__half2*>(&u.y);
        __half2 c = *reinterpret_cast<__half2*>(&u.z);
        __half2 d = *reinterpret_cast<__half2*>(&u.w);
        float4 f0, f1;
        f0.x = __half2float(a.x);  f0.y = __half2float(a.y);
        f0.z = __half2float(b.x);  f0.w = __half2float(b.y);
        f1.x = __half2float(c.x);  f1.y = __half2float(c.y);
        f1.z = __half2float(d.x);  f1.w = __half2float(d.y);
        *reinterpret_cast<float4*>(ob + i * 8192 + t * 8)     = f0;
        *reinterpret_cast<float4*>(ob + i * 8192 + t * 8 + 4) = f1;
    }
}

// ---------------- fallbacks (map8 = 148us known-good) ----------------
__global__ void __launch_bounds__(256)
build_pk(const float* __restrict__ filters,
         const int*   __restrict__ ind,
         unsigned* __restrict__ pk) {
    int t = blockIdx.x * 256 + threadIdx.x;
    if (t >= D_ALL) return;
    int m = t >> 9, r = t & 511;
    int idx = ind[r * D_ROW + m];
    __half hw = __float2half_rn(filters[(size_t)r * D_ALL + idx]);
    pk[t] = ((unsigned)__half_as_ushort(hw) << 16) | (unsigned)idx;
}

__device__ __forceinline__ float map_one(const __half* xs, unsigned p) {
    return __half2float(xs[p & 0xffffu]) *
           __half2float(__ushort_as_half((unsigned short)(p >> 16)));
}
__device__ __forceinline__ unsigned h2bits(float a, float b) {
    __half2 h = __floats2half2_rn(a, b);
    return *reinterpret_cast<unsigned*>(&h);
}

__global__ void __launch_bounds__(1024, 4)
map8(const float* __restrict__ x, const uint4* __restrict__ pk4,
     float* __restrict__ out) {
    __shared__ __half xs[D_ALL];
    const int t = threadIdx.x;
    const int row0 = blockIdx.x * 4;
    float4 buf[16];
    {
        const float4* src = reinterpret_cast<const float4*>(x + ((size_t)row0 << 16));
        #pragma unroll
        for (int i = 0; i < 8; ++i) {
            buf[2 * i]     = src[i * 2048 + t * 2];
            buf[2 * i + 1] = src[i * 2048 + t * 2 + 1];
        }
    }
    #pragma unroll
    for (int k = 0; k < 4; ++k) {
        #pragma unroll
        for (int i = 0; i < 8; ++i) {
            uint4 u;
            u.x = h2bits(buf[2 * i].x,     buf[2 * i].y);
            u.y = h2bits(buf[2 * i].z,     buf[2 * i].w);
            u.z = h2bits(buf[2 * i + 1].x, buf[2 * i + 1].y);
            u.w = h2bits(buf[2 * i + 1].z, buf[2 * i + 1].w);
            *reinterpret_cast<uint4*>(xs + (size_t)(i * 2048 + t * 2) * 4) = u;
        }
        lds_barrier();
        float* ob = out + ((size_t)(row0 + k) << 16);
        #pragma unroll 4
        for (int j = 0; j < 16; ++j) {
            uint4 p = pk4[j * 1024 + t];
            float4 r;
            r.x = map_one(xs, p.x); r.y = map_one(xs, p.y);
            r.z = map_one(xs, p.z); r.w = map_one(xs, p.w);
            *reinterpret_cast<float4*>(ob + j * 4096 + t * 4) = r;
        }
        __builtin_amdgcn_sched_barrier(0);
        if (k + 1 < 4) {
            const float4* src = reinterpret_cast<const float4*>(
                x + ((size_t)(row0 + k + 1) << 16));
            #pragma unroll
            for (int i = 0; i < 8; ++i) {
                buf[2 * i]     = src[i * 2048 + t * 2];
                buf[2 * i + 1] = src[i * 2048 + t * 2 + 1];
            }
        }
        __builtin_amdgcn_sched_barrier(0);
        lds_barrier();
    }
}

__global__ void __launch_bounds__(256)
map_kernel_nows(const float* __restrict__ x,
                const float* __restrict__ filters,
                const int*   __restrict__ ind,
                float*       __restrict__ out) {
    size_t o = (size_t)blockIdx.x * 256 + threadIdx.x;
    if (o >= (size_t)BATCH * D_ALL) return;
    unsigned b = (unsigned)(o >> 16);
    unsigned rem = (unsigned)(o & 65535u);
    unsigned m = rem >> 9, r = rem & 511u;
    int idx = ind[r * D_ROW + m];
    out[o] = x[((size_t)b << 16) + idx] * filters[(size_t)r * D_ALL + idx];
}

extern "C" void kernel_launch(void* const* d_in, const int* in_sizes, int n_in,
                              void* d_out, int out_size, void* d_ws, size_t ws_size,
                              hipStream_t stream) {
    const float* x       = (const float*)d_in[0];
    const float* filters = (const float*)d_in[1];
    const int*   ind     = (const int*)d_in[2];
    float*       out     = (float*)d_out;

    // ws layout for map10
    const size_t off_offs = 0;                               // u32[65536]
    const size_t off_part = off_offs + (size_t)D_ALL * 4;    // u32[64] (+pad to 256)
    const size_t off_ir   = off_part + 256;                  // u32[65536]
    const size_t off_w    = off_ir + (size_t)D_ALL * 4;      // u16[65536]
    const size_t need10   = off_w + (size_t)D_ALL * 2;       // ~896 KB
    const size_t need8    = (size_t)D_ALL * sizeof(unsigned);

    if (ws_size >= need10) {
        unsigned* offs = (unsigned*)((char*)d_ws + off_offs);
        unsigned* part = (unsigned*)((char*)d_ws + off_part);
        unsigned* irb  = (unsigned*)((char*)d_ws + off_ir);
        unsigned short* wbuf = (unsigned short*)((char*)d_ws + off_w);
        k_zero   <<<64, 1024, 0, stream>>>(offs);
        k_hist   <<<64, 1024, 0, stream>>>(ind, offs);
        k_scan1  <<<64, 1024, 0, stream>>>(offs, part);
        k_scan2  <<<1,    64, 0, stream>>>(part);
        k_scatter<<<64, 1024, 0, stream>>>(filters, ind, offs, part, irb, wbuf);
        map10<<<BATCH, 1024, 0, stream>>>(
            x, reinterpret_cast<const uint4*>(irb),
            reinterpret_cast<const ushort4*>(wbuf), out);
    } else if (ws_size >= need8) {
        unsigned* pk = (unsigned*)d_ws;
        build_pk<<<D_ALL / 256, 256, 0, stream>>>(filters, ind, pk);
        map8<<<BATCH / 4, 1024, 0, stream>>>(
            x, reinterpret_cast<const uint4*>(pk), out);
    } else {
        map_kernel_nows<<<(BATCH * (size_t)D_ALL) / 256, 256, 0, stream>>>(
            x, filters, ind, out);
    }
}